// Round 2
// baseline (201.181 us; speedup 1.0000x reference)
//
#include <hip/hip_runtime.h>

#define T 8192
#define BATCH 512
#define NTH 512
#define EPT 16
#define NW 8

template <int N>
__device__ __forceinline__ void block_reduce(float (&v)[N], float* s_red, float* s_bc) {
    int lane = threadIdx.x & 63, wid = threadIdx.x >> 6;
#pragma unroll
    for (int j = 0; j < N; j++) {
        float x = v[j];
#pragma unroll
        for (int off = 32; off; off >>= 1) x += __shfl_xor(x, off);
        if (lane == 0) s_red[wid * N + j] = x;
    }
    __syncthreads();
    if (threadIdx.x < N) {
        float s = 0.f;
#pragma unroll
        for (int w = 0; w < NW; w++) s += s_red[w * N + threadIdx.x];
        s_bc[threadIdx.x] = s;
    }
    __syncthreads();
}

__global__ __launch_bounds__(NTH, 4) void teacher_kernel(
    const float* __restrict__ dur, const float* __restrict__ stats,
    const float* __restrict__ trace, const float* __restrict__ mask,
    const float* __restrict__ cue, float* __restrict__ out)
{
    const int row = blockIdx.x;
    if (row >= BATCH) return;
    const int tid = threadIdx.x;
    const int lane = tid & 63, wid = tid >> 6;

    __shared__ unsigned s_hist[2 * NW * 256];   // 16 KB ping-pong
    __shared__ float s_red[NW * 13];
    __shared__ float s_bc[16];
    __shared__ float s_cedge[NW][EPT];          // lane-0 cue per (wave, chunk)
    __shared__ float s_vL[NW][EPT], s_vR[NW][EPT];
    __shared__ float s_part[EPT * NW];
    __shared__ float s_offs[EPT * NW];
    __shared__ unsigned s_sel[4];
    __shared__ unsigned s_wu[NW];

    const size_t BT = (size_t)BATCH * T;
    const size_t rbase = (size_t)row * T;
    const float* drow = dur + rbase;
    const float* mrow = mask + rbase;
    const float* crow = cue + rbase;
    const float4* trow = (const float4*)(trace + rbase * 4);

    float* o_spe = out + rbase;
    float* o_pae = out + BT + rbase;
    float* o_sb  = out + 2 * BT;
    float* o_pb  = out + 2 * BT + BATCH;
    float* o_al  = out + 2 * BT + 2 * BATCH + rbase;
    float* o_cf  = out + 3 * BT + 2 * BATCH;
    float4* o_tc = ((float4*)(out + 3 * BT + 3 * BATCH)) + rbase;
    float* o_pc  = out + 7 * BT + 3 * BATCH + rbase;
    float* o_bk  = out + 8 * BT + 3 * BATCH + rbase;

    float durr[EPT], cuer[EPT], rb[EPT];

    // ---- Phase 1: single full input read, write trace_ctx, 12 masked sums + stats max
    float statmax = fminf(fmaxf(stats[tid * 5 + 4], 0.f), 1.f);  // NTH == BATCH
    float acc[12];
#pragma unroll
    for (int j = 0; j < 12; j++) acc[j] = 0.f;
#pragma unroll
    for (int i = 0; i < EPT; i++) {
        int t = i * NTH + tid;
        float m = mrow[t];
        float d = drow[t];
        float c = crow[t];
        float4 tr = trow[t];
        durr[i] = d; cuer[i] = c; rb[i] = tr.z;
        if (lane == 0) s_cedge[wid][i] = c;
        o_tc[t] = make_float4(tr.x * m, tr.y * m, tr.z * m, tr.w * m);
        acc[0] += m;            acc[1] += d * m;
        acc[2] += tr.x * m;     acc[3] += tr.x * tr.x * m;
        acc[4] += tr.y * m;     acc[5] += tr.y * tr.y * m;
        acc[6] += tr.z * m;     acc[7] += tr.z * tr.z * m;
        acc[8] += tr.w * m;     acc[9] += tr.w * tr.w * m;
        acc[10] += c * m;       acc[11] += c * c * m;
    }
    {
#pragma unroll
        for (int j = 0; j < 12; j++) {
            float x = acc[j];
#pragma unroll
            for (int off = 32; off; off >>= 1) x += __shfl_xor(x, off);
            if (lane == 0) s_red[wid * 13 + j] = x;
        }
        float mx = statmax;
#pragma unroll
        for (int off = 32; off; off >>= 1) mx = fmaxf(mx, __shfl_xor(mx, off));
        if (lane == 0) s_red[wid * 13 + 12] = mx;
        __syncthreads();
        if (tid < 13) {
            float s = s_red[tid];
#pragma unroll
            for (int w = 1; w < NW; w++) {
                float x = s_red[w * 13 + tid];
                s = (tid == 12) ? fmaxf(s, x) : (s + x);
            }
            s_bc[tid] = s;
        }
        __syncthreads();
    }
    const float visible = fmaxf(s_bc[0], 1.f);
    const float sum_d = s_bc[1];
    const float inv_vis = 1.f / visible;
    const float mean0 = s_bc[2] * inv_vis, ex20 = s_bc[3] * inv_vis;
    const float mean1 = s_bc[4] * inv_vis, ex21 = s_bc[5] * inv_vis;
    const float mean2 = s_bc[6] * inv_vis, ex22 = s_bc[7] * inv_vis;
    const float mean3 = s_bc[8] * inv_vis, ex23 = s_bc[9] * inv_vis;
    const float meanc = s_bc[10] * inv_vis, ex2c = s_bc[11] * inv_vis;
    const float gmax = s_bc[12];

    const float var1_raw = ex21 - mean1 * mean1;
    const float istd0 = 1.f / sqrtf(fmaxf(ex20 - mean0 * mean0, 1e-6f));
    const float istd1 = 1.f / sqrtf(fmaxf(var1_raw, 1e-6f));
    const float istd2 = 1.f / sqrtf(fmaxf(ex22 - mean2 * mean2, 1e-6f));
    const float istd3 = 1.f / sqrtf(fmaxf(ex23 - mean3 * mean3, 1e-6f));
    const float istdc = 1.f / sqrtf(fmaxf(ex2c - meanc * meanc, 1e-6f));

    const int L = (int)(visible + 0.5f);

    const float st0 = stats[row * 5 + 0], st1 = stats[row * 5 + 1];
    const float st2 = stats[row * 5 + 2], st4 = stats[row * 5 + 4];

    const float src_total = fmaxf(sum_d, 1.f);
    const float src_mean = src_total * inv_vis;
    const float ref_ms = fmaxf(st2, 1.f);
    const float rate_scale = fminf(fmaxf(ref_ms / fmaxf(src_mean, 1.f), 0.55f), 1.95f);
    const float speech_budget = src_total * rate_scale;
    const float pause_ratio = fminf(fmaxf(st0, 0.f), 0.49f);
    const float boundary_ratio = fminf(fmaxf(st4, 0.f), 1.f);
    const float mean_pause = fmaxf(st1, 0.f);
    const float pfr = speech_budget * pause_ratio / fmaxf(1.f - pause_ratio, 0.2f);
    const float pfe = visible * boundary_ratio * mean_pause;
    float pause_budget = fmaxf(0.35f * pfr + 0.65f * pfe, 0.f);
    pause_budget = fminf(pause_budget, speech_budget * 0.8f);

    float conf = 0.2f + 0.3f * fminf(fmaxf(st0, 0.f), 1.f)
               + 0.25f * fminf(fmaxf(st4, 0.f), 1.f)
               + 0.2f * mean2
               + 0.1f * expf(-fmaxf(var1_raw, 0.f)) + 0.05f;
    conf = fminf(fmaxf(conf, 0.05f), 1.f);

    const float ratio = fminf(fmaxf(fmaxf(0.3f, gmax), 0.f), 1.f);
    int kint = (int)rintf(visible * ratio);
    kint = max(1, min(kint, L));

    // ---- Phase 2: rb (in place), cosine reduction, gate
    float acc3[3] = {0.f, 0.f, 0.f};
#pragma unroll
    for (int i = 0; i < EPT; i++) {
        int t = i * NTH + tid;
        float spv = 0.f, rbv = 0.f;
        if (t < L) {
            spv = fminf(fmaxf((cuer[i] - meanc) * istdc, -1.5f), 1.5f);
            rbv = (rb[i] - mean2) * istd2;
        }
        rb[i] = rbv;
        acc3[0] += spv * rbv; acc3[1] += spv * spv; acc3[2] += rbv * rbv;
    }
    block_reduce<3>(acc3, s_red, s_bc);
    float pcoef;
    {
        float dotv = s_bc[0];
        float xn = sqrtf(fmaxf(s_bc[1], 1e-6f));
        float yn = sqrtf(fmaxf(s_bc[2], 1e-6f));
        float agree = fminf(fmaxf(dotv / fmaxf(xn * yn, 1e-6f), -1.f), 1.f);
        float gate = 1.f / (1.f + expf(-(agree - 0.15f) * 4.f));
        pcoef = 0.35f * (0.05f + 0.5f * gate);
    }

    // ---- Phase 3: merged speech-score + pause-score pass (one coalesced trace reload)
    float v[EPT], ps[EPT];
#pragma unroll
    for (int i = 0; i < EPT; i++) {
        int t = i * NTH + tid;
        float4 tr = trow[t];
        float cr = __shfl_down(cuer[i], 1);
        if (lane == 63)
            cr = (wid < NW - 1) ? s_cedge[wid + 1][i]
                                : ((i + 1 < EPT) ? s_cedge[0][i + 1] : 1.f);
        float vv = 0.f, pp = 0.f;
        if (t < L) {
            float z1 = (tr.y - mean1) * istd1;
            float z3 = (tr.w - mean3) * istd3;
            vv = expf(log1pf(fmaxf(durr[i], 0.f)) + 0.45f * z1 + 0.3f * z3 + 0.2f * cr);
            float z0 = (tr.x - mean0) * istd0;
            float spv = fminf(fmaxf((cuer[i] - meanc) * istdc, -1.5f), 1.5f);
            pp = expf(1.1f * z0 + 1.5f * rb[i] + pcoef * spv);
        }
        v[i] = vv; ps[i] = pp;
        if (lane == 0)  s_vL[wid][i] = vv;
        if (lane == 63) s_vR[wid][i] = vv;
    }
    // clear radix hist buffer 0 under the same barrier
    for (int j = tid; j < NW * 256; j += NTH) s_hist[j] = 0u;
    __syncthreads();

    // ---- Phase 3b: smooth3 via shuffles + edges, sum
    float sm[EPT];
    float acc1[1] = {0.f};
#pragma unroll
    for (int i = 0; i < EPT; i++) {
        int t = i * NTH + tid;
        float vl = __shfl_up(v[i], 1);
        if (lane == 0)
            vl = (wid > 0) ? s_vR[wid - 1][i] : ((i > 0) ? s_vR[NW - 1][i - 1] : 0.f);
        float vr = __shfl_down(v[i], 1);
        if (lane == 63)
            vr = (wid < NW - 1) ? s_vL[wid + 1][i] : ((i + 1 < EPT) ? s_vL[0][i + 1] : 0.f);
        float smv = 0.f;
        if (t < L) smv = (vl + v[i] + vr) * (1.f / 3.f);
        sm[i] = smv; acc1[0] += smv;
    }
    block_reduce<1>(acc1, s_red, s_bc);
    const float spe_scale = speech_budget / fmaxf(s_bc[0], 1e-6f);

    // ---- Phase 4: exact radix select, ping-pong histograms (2 barriers/round)
    unsigned pref = 0u, cmaskk = 0u;
    unsigned kk = (unsigned)kint;
    unsigned cnt_eq = 0u;
    int cur = 0;
#pragma unroll 1
    for (int r = 0; r < 4; r++) {
        const int shift = 24 - 8 * r;
#pragma unroll
        for (int i = 0; i < EPT; i++) {
            unsigned b = __float_as_uint(ps[i]);
            if ((b & cmaskk) == pref)
                atomicAdd(&s_hist[cur * (NW * 256) + wid * 256 + ((b >> shift) & 0xFFu)], 1u);
        }
        __syncthreads();
        if (wid == 0) {
            unsigned base = lane * 4;
            unsigned h0 = 0, h1 = 0, h2 = 0, h3 = 0;
#pragma unroll
            for (int w = 0; w < NW; w++) {
                const unsigned* hb = &s_hist[cur * (NW * 256) + w * 256 + base];
                h0 += hb[0]; h1 += hb[1]; h2 += hb[2]; h3 += hb[3];
            }
            unsigned s = h0 + h1 + h2 + h3;
            unsigned vs = s;
#pragma unroll
            for (int off = 1; off < 64; off <<= 1) {
                unsigned u = __shfl_down(vs, off);
                if (lane + off < 64) vs += u;
            }
            unsigned vnext = __shfl_down(vs, 1);
            if (lane == 63) vnext = 0u;
            unsigned higher = vs - s;
            unsigned S3 = higher + h3;
            unsigned S2 = S3 + h2;
            unsigned S1 = S2 + h1;
            unsigned S0 = S1 + h0;
            if (S3 >= kk && vnext < kk)    { s_sel[0] = base + 3; s_sel[1] = vnext; s_sel[2] = S3; }
            else if (S2 >= kk && S3 < kk)  { s_sel[0] = base + 2; s_sel[1] = S3;    s_sel[2] = S2; }
            else if (S1 >= kk && S2 < kk)  { s_sel[0] = base + 1; s_sel[1] = S2;    s_sel[2] = S1; }
            else if (S0 >= kk && S1 < kk)  { s_sel[0] = base + 0; s_sel[1] = S1;    s_sel[2] = S0; }
        } else if (r < 3) {
            // other waves clear the next buffer while wave 0 scans
            for (int j = tid - 64; j < NW * 256; j += NTH - 64)
                s_hist[(cur ^ 1) * (NW * 256) + j] = 0u;
        }
        __syncthreads();
        pref |= s_sel[0] << shift;
        cmaskk |= 0xFFu << shift;
        kk -= s_sel[1];
        if (r == 3) cnt_eq = s_sel[2] - s_sel[1];
        cur ^= 1;
    }
    const unsigned thr_bits = pref;
    const unsigned keep_eq = kk;

    // ---- Phase 5: keep top-k (stable tie-break only if needed), sum kept
    float accp[1] = {0.f};
    if (cnt_eq == keep_eq) {
#pragma unroll
        for (int c = 0; c < EPT; c++) {
            unsigned b = __float_as_uint(ps[c]);
            float pv = (b >= thr_bits) ? ps[c] : 0.f;
            ps[c] = pv; accp[0] += pv;
        }
    } else {
        unsigned carry_eq = 0u;
#pragma unroll
        for (int c = 0; c < EPT; c++) {
            unsigned b = __float_as_uint(ps[c]);
            bool eq = (b == thr_bits);
            unsigned long long bal = __ballot(eq);
            unsigned lpre = (unsigned)__popcll(bal & ((1ull << lane) - 1ull));
            unsigned wc = (unsigned)__popcll(bal);
            if (lane == 0) s_wu[wid] = wc;
            __syncthreads();
            unsigned woff = 0u, tot = 0u;
#pragma unroll
            for (int w = 0; w < NW; w++) { unsigned x = s_wu[w]; if (w < wid) woff += x; tot += x; }
            __syncthreads();
            unsigned rank = carry_eq + woff + lpre;
            bool keep = (b > thr_bits) || (eq && rank < keep_eq);
            float pv = keep ? ps[c] : 0.f;
            ps[c] = pv; accp[0] += pv;
            carry_eq += tot;
        }
    }
    block_reduce<1>(accp, s_red, s_bc);
    const float pa_scale = pause_budget / fmaxf(s_bc[0], 1e-6f);

    // ---- Phase 6: writes + 2-barrier block scan
    const float inv_alloc = 1.f / fmaxf(speech_budget + pause_budget, 1e-6f);
#pragma unroll
    for (int c = 0; c < EPT; c++) {
        int t = c * NTH + tid;
        bool in = t < L;
        float spe = sm[c] * spe_scale;
        float pae = ps[c] * pa_scale;
        o_spe[t] = spe;
        o_pae[t] = pae;
        o_al[t] = (spe + pae) * inv_alloc;
        float x = in ? (spe + pae - durr[c]) : 0.f;
#pragma unroll
        for (int off = 1; off < 64; off <<= 1) {
            float u = __shfl_up(x, off);
            if (lane >= off) x += u;
        }
        sm[c] = x;                       // reuse: per-lane inclusive scan within wave
        if (lane == 63) s_part[c * NW + wid] = x;
    }
    __syncthreads();
    if (wid == 0) {
        float a = s_part[2 * lane], b = s_part[2 * lane + 1];
        float pair = a + b;
        float inc = pair;
#pragma unroll
        for (int off = 1; off < 64; off <<= 1) {
            float u = __shfl_up(inc, off);
            if (lane >= off) inc += u;
        }
        float excl = inc - pair;
        s_offs[2 * lane] = excl;
        s_offs[2 * lane + 1] = excl + a;
    }
    __syncthreads();
#pragma unroll
    for (int c = 0; c < EPT; c++) {
        int t = c * NTH + tid;
        bool in = t < L;
        float incl = s_offs[c * NW + wid] + sm[c];
        o_pc[t] = in ? incl : 0.f;
        o_bk[t] = in ? fmaxf(incl, 0.f) : 0.f;
    }

    if (tid == 0) {
        o_sb[row] = speech_budget;
        o_pb[row] = pause_budget;
        o_cf[row] = conf;
    }
}

extern "C" void kernel_launch(void* const* d_in, const int* in_sizes, int n_in,
                              void* d_out, int out_size, void* d_ws, size_t ws_size,
                              hipStream_t stream) {
    const float* dur   = (const float*)d_in[0];
    const float* stats = (const float*)d_in[1];
    const float* trace = (const float*)d_in[2];
    const float* mask  = (const float*)d_in[3];
    const float* cue   = (const float*)d_in[4];
    float* out = (float*)d_out;

    teacher_kernel<<<dim3(BATCH), dim3(NTH), 0, stream>>>(dur, stats, trace, mask, cue, out);
}

// Round 3
// 200.425 us; speedup vs baseline: 1.0038x; 1.0038x over previous
//
#include <hip/hip_runtime.h>

#define T 8192
#define BATCH 512
#define NTH 512
#define EPT 16
#define NW 8

template <int N>
__device__ __forceinline__ void block_reduce(float (&v)[N], float* s_red, float* s_bc) {
    int lane = threadIdx.x & 63, wid = threadIdx.x >> 6;
#pragma unroll
    for (int j = 0; j < N; j++) {
        float x = v[j];
#pragma unroll
        for (int off = 32; off; off >>= 1) x += __shfl_xor(x, off);
        if (lane == 0) s_red[wid * N + j] = x;
    }
    __syncthreads();
    if (threadIdx.x < N) {
        float s = 0.f;
#pragma unroll
        for (int w = 0; w < NW; w++) s += s_red[w * N + threadIdx.x];
        s_bc[threadIdx.x] = s;
    }
    __syncthreads();
}

__global__ void __launch_bounds__(NTH)
__attribute__((amdgpu_waves_per_eu(4, 4)))
teacher_kernel(
    const float* __restrict__ dur, const float* __restrict__ stats,
    const float* __restrict__ trace, const float* __restrict__ mask,
    const float* __restrict__ cue, float* __restrict__ out)
{
    const int row = blockIdx.x;
    const int tid = threadIdx.x;
    const int lane = tid & 63, wid = tid >> 6;

    __shared__ unsigned s_hist[2 * NW * 256];   // 16 KB ping-pong
    __shared__ float s_red[NW * 13];
    __shared__ float s_bc[16];
    __shared__ float s_cedge[NW][EPT];          // lane-0 cue per (wave, chunk)
    __shared__ float s_vL[NW][EPT], s_vR[NW][EPT];
    __shared__ float s_part[EPT * NW];
    __shared__ float s_offs[EPT * NW];
    __shared__ unsigned s_sel[4];
    __shared__ unsigned s_wu[NW];

    const size_t BT = (size_t)BATCH * T;
    const size_t rbase = (size_t)row * T;
    const float* drow = dur + rbase;
    const float* mrow = mask + rbase;
    const float* crow = cue + rbase;
    const float4* trow = (const float4*)(trace + rbase * 4);

    float* o_spe = out + rbase;
    float* o_pae = out + BT + rbase;
    float* o_sb  = out + 2 * BT;
    float* o_pb  = out + 2 * BT + BATCH;
    float* o_al  = out + 2 * BT + 2 * BATCH + rbase;
    float* o_cf  = out + 3 * BT + 2 * BATCH;
    float4* o_tc = ((float4*)(out + 3 * BT + 3 * BATCH)) + rbase;
    float* o_pc  = out + 7 * BT + 3 * BATCH + rbase;
    float* o_bk  = out + 8 * BT + 3 * BATCH + rbase;

    float durr[EPT], cuer[EPT], rb[EPT];

    // ---- Phase 1: single full input read, write trace_ctx, 12 masked sums + stats max
    float statmax = fminf(fmaxf(stats[tid * 5 + 4], 0.f), 1.f);  // NTH == BATCH
    float acc[12];
#pragma unroll
    for (int j = 0; j < 12; j++) acc[j] = 0.f;
#pragma unroll
    for (int i = 0; i < EPT; i++) {
        int t = i * NTH + tid;
        float m = mrow[t];
        float d = drow[t];
        float c = crow[t];
        float4 tr = trow[t];
        durr[i] = d; cuer[i] = c; rb[i] = tr.z;
        if (lane == 0) s_cedge[wid][i] = c;
        o_tc[t] = make_float4(tr.x * m, tr.y * m, tr.z * m, tr.w * m);
        acc[0] += m;            acc[1] += d * m;
        acc[2] += tr.x * m;     acc[3] += tr.x * tr.x * m;
        acc[4] += tr.y * m;     acc[5] += tr.y * tr.y * m;
        acc[6] += tr.z * m;     acc[7] += tr.z * tr.z * m;
        acc[8] += tr.w * m;     acc[9] += tr.w * tr.w * m;
        acc[10] += c * m;       acc[11] += c * c * m;
    }
    {
#pragma unroll
        for (int j = 0; j < 12; j++) {
            float x = acc[j];
#pragma unroll
            for (int off = 32; off; off >>= 1) x += __shfl_xor(x, off);
            if (lane == 0) s_red[wid * 13 + j] = x;
        }
        float mx = statmax;
#pragma unroll
        for (int off = 32; off; off >>= 1) mx = fmaxf(mx, __shfl_xor(mx, off));
        if (lane == 0) s_red[wid * 13 + 12] = mx;
        __syncthreads();
        if (tid < 13) {
            float s = s_red[tid];
#pragma unroll
            for (int w = 1; w < NW; w++) {
                float x = s_red[w * 13 + tid];
                s = (tid == 12) ? fmaxf(s, x) : (s + x);
            }
            s_bc[tid] = s;
        }
        __syncthreads();
    }
    const float visible = fmaxf(s_bc[0], 1.f);
    const float sum_d = s_bc[1];
    const float inv_vis = 1.f / visible;
    const float mean0 = s_bc[2] * inv_vis, ex20 = s_bc[3] * inv_vis;
    const float mean1 = s_bc[4] * inv_vis, ex21 = s_bc[5] * inv_vis;
    const float mean2 = s_bc[6] * inv_vis, ex22 = s_bc[7] * inv_vis;
    const float mean3 = s_bc[8] * inv_vis, ex23 = s_bc[9] * inv_vis;
    const float meanc = s_bc[10] * inv_vis, ex2c = s_bc[11] * inv_vis;
    const float gmax = s_bc[12];

    const float var1_raw = ex21 - mean1 * mean1;
    const float istd0 = 1.f / sqrtf(fmaxf(ex20 - mean0 * mean0, 1e-6f));
    const float istd1 = 1.f / sqrtf(fmaxf(var1_raw, 1e-6f));
    const float istd2 = 1.f / sqrtf(fmaxf(ex22 - mean2 * mean2, 1e-6f));
    const float istd3 = 1.f / sqrtf(fmaxf(ex23 - mean3 * mean3, 1e-6f));
    const float istdc = 1.f / sqrtf(fmaxf(ex2c - meanc * meanc, 1e-6f));

    const int L = (int)(visible + 0.5f);

    const float st0 = stats[row * 5 + 0], st1 = stats[row * 5 + 1];
    const float st2 = stats[row * 5 + 2], st4 = stats[row * 5 + 4];

    const float src_total = fmaxf(sum_d, 1.f);
    const float src_mean = src_total * inv_vis;
    const float ref_ms = fmaxf(st2, 1.f);
    const float rate_scale = fminf(fmaxf(ref_ms / fmaxf(src_mean, 1.f), 0.55f), 1.95f);
    const float speech_budget = src_total * rate_scale;
    const float pause_ratio = fminf(fmaxf(st0, 0.f), 0.49f);
    const float boundary_ratio = fminf(fmaxf(st4, 0.f), 1.f);
    const float mean_pause = fmaxf(st1, 0.f);
    const float pfr = speech_budget * pause_ratio / fmaxf(1.f - pause_ratio, 0.2f);
    const float pfe = visible * boundary_ratio * mean_pause;
    float pause_budget = fmaxf(0.35f * pfr + 0.65f * pfe, 0.f);
    pause_budget = fminf(pause_budget, speech_budget * 0.8f);

    float conf = 0.2f + 0.3f * fminf(fmaxf(st0, 0.f), 1.f)
               + 0.25f * fminf(fmaxf(st4, 0.f), 1.f)
               + 0.2f * mean2
               + 0.1f * expf(-fmaxf(var1_raw, 0.f)) + 0.05f;
    conf = fminf(fmaxf(conf, 0.05f), 1.f);

    const float ratio = fminf(fmaxf(fmaxf(0.3f, gmax), 0.f), 1.f);
    int kint = (int)rintf(visible * ratio);
    kint = max(1, min(kint, L));

    // ---- Phase 2: rb standardize (in place) + cosine reduction -> gate
    float acc3[3] = {0.f, 0.f, 0.f};
#pragma unroll
    for (int i = 0; i < EPT; i++) {
        int t = i * NTH + tid;
        float spv = 0.f, rbv = 0.f;
        if (t < L) {
            spv = fminf(fmaxf((cuer[i] - meanc) * istdc, -1.5f), 1.5f);
            rbv = (rb[i] - mean2) * istd2;
        }
        rb[i] = rbv;
        acc3[0] += spv * rbv; acc3[1] += spv * spv; acc3[2] += rbv * rbv;
    }
    block_reduce<3>(acc3, s_red, s_bc);
    float pcoef;
    {
        float dotv = s_bc[0];
        float xn = sqrtf(fmaxf(s_bc[1], 1e-6f));
        float yn = sqrtf(fmaxf(s_bc[2], 1e-6f));
        float agree = fminf(fmaxf(dotv / fmaxf(xn * yn, 1e-6f), -1.f), 1.f);
        float gate = 1.f / (1.f + expf(-(agree - 0.15f) * 4.f));
        pcoef = 0.35f * (0.05f + 0.5f * gate);
    }

    // ---- Phase 3: merged speech-score + pause-score pass (one coalesced trace reload)
    float v[EPT], ps[EPT];
#pragma unroll
    for (int i = 0; i < EPT; i++) {
        int t = i * NTH + tid;
        float4 tr = trow[t];
        float cr = __shfl_down(cuer[i], 1);
        if (lane == 63)
            cr = (wid < NW - 1) ? s_cedge[wid + 1][i]
                                : ((i + 1 < EPT) ? s_cedge[0][i + 1] : 1.f);
        float vv = 0.f, pp = 0.f;
        if (t < L) {
            float z1 = (tr.y - mean1) * istd1;
            float z3 = (tr.w - mean3) * istd3;
            vv = expf(log1pf(fmaxf(durr[i], 0.f)) + 0.45f * z1 + 0.3f * z3 + 0.2f * cr);
            float z0 = (tr.x - mean0) * istd0;
            float spv = fminf(fmaxf((cuer[i] - meanc) * istdc, -1.5f), 1.5f);
            pp = expf(1.1f * z0 + 1.5f * rb[i] + pcoef * spv);
        }
        v[i] = vv; ps[i] = pp;
        if (lane == 0)  s_vL[wid][i] = vv;
        if (lane == 63) s_vR[wid][i] = vv;
    }
    // clear radix hist buffer 0 under the same barrier
    for (int j = tid; j < NW * 256; j += NTH) s_hist[j] = 0u;
    __syncthreads();

    // ---- Phase 3b: smooth3 via shuffles + edges, sum
    float sm[EPT];
    float acc1[1] = {0.f};
#pragma unroll
    for (int i = 0; i < EPT; i++) {
        int t = i * NTH + tid;
        float vl = __shfl_up(v[i], 1);
        if (lane == 0)
            vl = (wid > 0) ? s_vR[wid - 1][i] : ((i > 0) ? s_vR[NW - 1][i - 1] : 0.f);
        float vr = __shfl_down(v[i], 1);
        if (lane == 63)
            vr = (wid < NW - 1) ? s_vL[wid + 1][i] : ((i + 1 < EPT) ? s_vL[0][i + 1] : 0.f);
        float smv = 0.f;
        if (t < L) smv = (vl + v[i] + vr) * (1.f / 3.f);
        sm[i] = smv; acc1[0] += smv;
    }
    block_reduce<1>(acc1, s_red, s_bc);
    const float spe_scale = speech_budget / fmaxf(s_bc[0], 1e-6f);

    // ---- Phase 4: exact radix select, ping-pong histograms (2 barriers/round)
    unsigned pref = 0u, cmaskk = 0u;
    unsigned kk = (unsigned)kint;
    unsigned cnt_eq = 0u;
    int cur = 0;
#pragma unroll 1
    for (int r = 0; r < 4; r++) {
        const int shift = 24 - 8 * r;
#pragma unroll
        for (int i = 0; i < EPT; i++) {
            unsigned b = __float_as_uint(ps[i]);
            if ((b & cmaskk) == pref)
                atomicAdd(&s_hist[cur * (NW * 256) + wid * 256 + ((b >> shift) & 0xFFu)], 1u);
        }
        __syncthreads();
        if (wid == 0) {
            unsigned base = lane * 4;
            unsigned h0 = 0, h1 = 0, h2 = 0, h3 = 0;
#pragma unroll
            for (int w = 0; w < NW; w++) {
                const unsigned* hb = &s_hist[cur * (NW * 256) + w * 256 + base];
                h0 += hb[0]; h1 += hb[1]; h2 += hb[2]; h3 += hb[3];
            }
            unsigned s = h0 + h1 + h2 + h3;
            unsigned vs = s;
#pragma unroll
            for (int off = 1; off < 64; off <<= 1) {
                unsigned u = __shfl_down(vs, off);
                if (lane + off < 64) vs += u;
            }
            unsigned vnext = __shfl_down(vs, 1);
            if (lane == 63) vnext = 0u;
            unsigned higher = vs - s;
            unsigned S3 = higher + h3;
            unsigned S2 = S3 + h2;
            unsigned S1 = S2 + h1;
            unsigned S0 = S1 + h0;
            if (S3 >= kk && vnext < kk)    { s_sel[0] = base + 3; s_sel[1] = vnext; s_sel[2] = S3; }
            else if (S2 >= kk && S3 < kk)  { s_sel[0] = base + 2; s_sel[1] = S3;    s_sel[2] = S2; }
            else if (S1 >= kk && S2 < kk)  { s_sel[0] = base + 1; s_sel[1] = S2;    s_sel[2] = S1; }
            else if (S0 >= kk && S1 < kk)  { s_sel[0] = base + 0; s_sel[1] = S1;    s_sel[2] = S0; }
        } else if (r < 3) {
            // other waves clear the next buffer while wave 0 scans
            for (int j = tid - 64; j < NW * 256; j += NTH - 64)
                s_hist[(cur ^ 1) * (NW * 256) + j] = 0u;
        }
        __syncthreads();
        pref |= s_sel[0] << shift;
        cmaskk |= 0xFFu << shift;
        kk -= s_sel[1];
        if (r == 3) cnt_eq = s_sel[2] - s_sel[1];
        cur ^= 1;
    }
    const unsigned thr_bits = pref;
    const unsigned keep_eq = kk;

    // ---- Phase 5: keep top-k (stable tie-break only if needed), sum kept
    float accp[1] = {0.f};
    if (cnt_eq == keep_eq) {
#pragma unroll
        for (int c = 0; c < EPT; c++) {
            unsigned b = __float_as_uint(ps[c]);
            float pv = (b >= thr_bits) ? ps[c] : 0.f;
            ps[c] = pv; accp[0] += pv;
        }
    } else {
        unsigned carry_eq = 0u;
#pragma unroll
        for (int c = 0; c < EPT; c++) {
            unsigned b = __float_as_uint(ps[c]);
            bool eq = (b == thr_bits);
            unsigned long long bal = __ballot(eq);
            unsigned lpre = (unsigned)__popcll(bal & ((1ull << lane) - 1ull));
            unsigned wc = (unsigned)__popcll(bal);
            if (lane == 0) s_wu[wid] = wc;
            __syncthreads();
            unsigned woff = 0u, tot = 0u;
#pragma unroll
            for (int w = 0; w < NW; w++) { unsigned x = s_wu[w]; if (w < wid) woff += x; tot += x; }
            __syncthreads();
            unsigned rank = carry_eq + woff + lpre;
            bool keep = (b > thr_bits) || (eq && rank < keep_eq);
            float pv = keep ? ps[c] : 0.f;
            ps[c] = pv; accp[0] += pv;
            carry_eq += tot;
        }
    }
    block_reduce<1>(accp, s_red, s_bc);
    const float pa_scale = pause_budget / fmaxf(s_bc[0], 1e-6f);

    // ---- Phase 6: writes + 2-barrier block scan
    const float inv_alloc = 1.f / fmaxf(speech_budget + pause_budget, 1e-6f);
#pragma unroll
    for (int c = 0; c < EPT; c++) {
        int t = c * NTH + tid;
        bool in = t < L;
        float spe = sm[c] * spe_scale;
        float pae = ps[c] * pa_scale;
        o_spe[t] = spe;
        o_pae[t] = pae;
        o_al[t] = (spe + pae) * inv_alloc;
        float x = in ? (spe + pae - durr[c]) : 0.f;
#pragma unroll
        for (int off = 1; off < 64; off <<= 1) {
            float u = __shfl_up(x, off);
            if (lane >= off) x += u;
        }
        sm[c] = x;                       // reuse: per-lane inclusive scan within wave
        if (lane == 63) s_part[c * NW + wid] = x;
    }
    __syncthreads();
    if (wid == 0) {
        float a = s_part[2 * lane], b = s_part[2 * lane + 1];
        float pair = a + b;
        float inc = pair;
#pragma unroll
        for (int off = 1; off < 64; off <<= 1) {
            float u = __shfl_up(inc, off);
            if (lane >= off) inc += u;
        }
        float excl = inc - pair;
        s_offs[2 * lane] = excl;
        s_offs[2 * lane + 1] = excl + a;
    }
    __syncthreads();
#pragma unroll
    for (int c = 0; c < EPT; c++) {
        int t = c * NTH + tid;
        bool in = t < L;
        float incl = s_offs[c * NW + wid] + sm[c];
        o_pc[t] = in ? incl : 0.f;
        o_bk[t] = in ? fmaxf(incl, 0.f) : 0.f;
    }

    if (tid == 0) {
        o_sb[row] = speech_budget;
        o_pb[row] = pause_budget;
        o_cf[row] = conf;
    }
}

extern "C" void kernel_launch(void* const* d_in, const int* in_sizes, int n_in,
                              void* d_out, int out_size, void* d_ws, size_t ws_size,
                              hipStream_t stream) {
    const float* dur   = (const float*)d_in[0];
    const float* stats = (const float*)d_in[1];
    const float* trace = (const float*)d_in[2];
    const float* mask  = (const float*)d_in[3];
    const float* cue   = (const float*)d_in[4];
    float* out = (float*)d_out;

    teacher_kernel<<<dim3(BATCH), dim3(NTH), 0, stream>>>(dur, stats, trace, mask, cue, out);
}

// Round 4
// 94.537 us; speedup vs baseline: 2.1281x; 2.1201x over previous
//
#include <hip/hip_runtime.h>

#define T 8192
#define BATCH 512
#define NTH 1024
#define EPT 8
#define NW 16

template <int N>
__device__ __forceinline__ void block_reduce(float (&v)[N], float* s_red, float* s_bc) {
    int lane = threadIdx.x & 63, wid = threadIdx.x >> 6;
#pragma unroll
    for (int j = 0; j < N; j++) {
        float x = v[j];
#pragma unroll
        for (int off = 32; off; off >>= 1) x += __shfl_xor(x, off);
        if (lane == 0) s_red[wid * N + j] = x;
    }
    __syncthreads();
    if (threadIdx.x < N) {
        float s = 0.f;
#pragma unroll
        for (int w = 0; w < NW; w++) s += s_red[w * N + threadIdx.x];
        s_bc[threadIdx.x] = s;
    }
    __syncthreads();
}

__global__ __launch_bounds__(NTH) void teacher_kernel(
    const float* __restrict__ dur, const float* __restrict__ stats,
    const float* __restrict__ trace, const float* __restrict__ mask,
    const float* __restrict__ cue, float* __restrict__ out)
{
    const int row = blockIdx.x;
    const int tid = threadIdx.x;
    const int lane = tid & 63, wid = tid >> 6;

    __shared__ unsigned s_hist[2 * NW * 256];   // 32 KB ping-pong
    __shared__ float s_red[NW * 13];
    __shared__ float s_bc[16];
    __shared__ float s_cedge[NW][EPT];          // lane-0 cue per (wave, chunk)
    __shared__ float s_vL[NW][EPT], s_vR[NW][EPT];
    __shared__ float s_part[EPT * NW];
    __shared__ float s_offs[EPT * NW];
    __shared__ unsigned s_sel[4];
    __shared__ unsigned s_wu[NW];

    const size_t BT = (size_t)BATCH * T;
    const size_t rbase = (size_t)row * T;
    const float* drow = dur + rbase;
    const float* mrow = mask + rbase;
    const float* crow = cue + rbase;
    const float4* trow = (const float4*)(trace + rbase * 4);

    float* o_spe = out + rbase;
    float* o_pae = out + BT + rbase;
    float* o_sb  = out + 2 * BT;
    float* o_pb  = out + 2 * BT + BATCH;
    float* o_al  = out + 2 * BT + 2 * BATCH + rbase;
    float* o_cf  = out + 3 * BT + 2 * BATCH;
    float4* o_tc = ((float4*)(out + 3 * BT + 3 * BATCH)) + rbase;
    float* o_pc  = out + 7 * BT + 3 * BATCH + rbase;
    float* o_bk  = out + 8 * BT + 3 * BATCH + rbase;

    float durr[EPT], cuer[EPT], rb[EPT];

    // ---- Phase 1: single full input read, write trace_ctx, 12 masked sums + stats max
    float statmax = (tid < BATCH) ? fminf(fmaxf(stats[tid * 5 + 4], 0.f), 1.f) : 0.f;
    float acc[12];
#pragma unroll
    for (int j = 0; j < 12; j++) acc[j] = 0.f;
#pragma unroll
    for (int i = 0; i < EPT; i++) {
        int t = i * NTH + tid;
        float m = mrow[t];
        float d = drow[t];
        float c = crow[t];
        float4 tr = trow[t];
        durr[i] = d; cuer[i] = c; rb[i] = tr.z;
        if (lane == 0) s_cedge[wid][i] = c;
        o_tc[t] = make_float4(tr.x * m, tr.y * m, tr.z * m, tr.w * m);
        acc[0] += m;            acc[1] += d * m;
        acc[2] += tr.x * m;     acc[3] += tr.x * tr.x * m;
        acc[4] += tr.y * m;     acc[5] += tr.y * tr.y * m;
        acc[6] += tr.z * m;     acc[7] += tr.z * tr.z * m;
        acc[8] += tr.w * m;     acc[9] += tr.w * tr.w * m;
        acc[10] += c * m;       acc[11] += c * c * m;
    }
    {
#pragma unroll
        for (int j = 0; j < 12; j++) {
            float x = acc[j];
#pragma unroll
            for (int off = 32; off; off >>= 1) x += __shfl_xor(x, off);
            if (lane == 0) s_red[wid * 13 + j] = x;
        }
        float mx = statmax;
#pragma unroll
        for (int off = 32; off; off >>= 1) mx = fmaxf(mx, __shfl_xor(mx, off));
        if (lane == 0) s_red[wid * 13 + 12] = mx;
        __syncthreads();
        if (tid < 13) {
            float s = s_red[tid];
#pragma unroll
            for (int w = 1; w < NW; w++) {
                float x = s_red[w * 13 + tid];
                s = (tid == 12) ? fmaxf(s, x) : (s + x);
            }
            s_bc[tid] = s;
        }
        __syncthreads();
    }
    const float visible = fmaxf(s_bc[0], 1.f);
    const float sum_d = s_bc[1];
    const float inv_vis = 1.f / visible;
    const float mean0 = s_bc[2] * inv_vis, ex20 = s_bc[3] * inv_vis;
    const float mean1 = s_bc[4] * inv_vis, ex21 = s_bc[5] * inv_vis;
    const float mean2 = s_bc[6] * inv_vis, ex22 = s_bc[7] * inv_vis;
    const float mean3 = s_bc[8] * inv_vis, ex23 = s_bc[9] * inv_vis;
    const float meanc = s_bc[10] * inv_vis, ex2c = s_bc[11] * inv_vis;
    const float gmax = s_bc[12];

    const float var1_raw = ex21 - mean1 * mean1;
    const float istd0 = 1.f / sqrtf(fmaxf(ex20 - mean0 * mean0, 1e-6f));
    const float istd1 = 1.f / sqrtf(fmaxf(var1_raw, 1e-6f));
    const float istd2 = 1.f / sqrtf(fmaxf(ex22 - mean2 * mean2, 1e-6f));
    const float istd3 = 1.f / sqrtf(fmaxf(ex23 - mean3 * mean3, 1e-6f));
    const float istdc = 1.f / sqrtf(fmaxf(ex2c - meanc * meanc, 1e-6f));

    const int L = (int)(visible + 0.5f);

    const float st0 = stats[row * 5 + 0], st1 = stats[row * 5 + 1];
    const float st2 = stats[row * 5 + 2], st4 = stats[row * 5 + 4];

    const float src_total = fmaxf(sum_d, 1.f);
    const float src_mean = src_total * inv_vis;
    const float ref_ms = fmaxf(st2, 1.f);
    const float rate_scale = fminf(fmaxf(ref_ms / fmaxf(src_mean, 1.f), 0.55f), 1.95f);
    const float speech_budget = src_total * rate_scale;
    const float pause_ratio = fminf(fmaxf(st0, 0.f), 0.49f);
    const float boundary_ratio = fminf(fmaxf(st4, 0.f), 1.f);
    const float mean_pause = fmaxf(st1, 0.f);
    const float pfr = speech_budget * pause_ratio / fmaxf(1.f - pause_ratio, 0.2f);
    const float pfe = visible * boundary_ratio * mean_pause;
    float pause_budget = fmaxf(0.35f * pfr + 0.65f * pfe, 0.f);
    pause_budget = fminf(pause_budget, speech_budget * 0.8f);

    float conf = 0.2f + 0.3f * fminf(fmaxf(st0, 0.f), 1.f)
               + 0.25f * fminf(fmaxf(st4, 0.f), 1.f)
               + 0.2f * mean2
               + 0.1f * expf(-fmaxf(var1_raw, 0.f)) + 0.05f;
    conf = fminf(fmaxf(conf, 0.05f), 1.f);

    const float ratio = fminf(fmaxf(fmaxf(0.3f, gmax), 0.f), 1.f);
    int kint = (int)rintf(visible * ratio);
    kint = max(1, min(kint, L));

    // ---- Phase 2: rb standardize (in place) + cosine reduction -> gate
    float acc3[3] = {0.f, 0.f, 0.f};
#pragma unroll
    for (int i = 0; i < EPT; i++) {
        int t = i * NTH + tid;
        float spv = 0.f, rbv = 0.f;
        if (t < L) {
            spv = fminf(fmaxf((cuer[i] - meanc) * istdc, -1.5f), 1.5f);
            rbv = (rb[i] - mean2) * istd2;
        }
        rb[i] = rbv;
        acc3[0] += spv * rbv; acc3[1] += spv * spv; acc3[2] += rbv * rbv;
    }
    block_reduce<3>(acc3, s_red, s_bc);
    float pcoef;
    {
        float dotv = s_bc[0];
        float xn = sqrtf(fmaxf(s_bc[1], 1e-6f));
        float yn = sqrtf(fmaxf(s_bc[2], 1e-6f));
        float agree = fminf(fmaxf(dotv / fmaxf(xn * yn, 1e-6f), -1.f), 1.f);
        float gate = 1.f / (1.f + expf(-(agree - 0.15f) * 4.f));
        pcoef = 0.35f * (0.05f + 0.5f * gate);
    }

    // ---- Phase 3: merged speech + pause scores (one coalesced trace reload; L3-hot)
    float v[EPT], ps[EPT];
#pragma unroll
    for (int i = 0; i < EPT; i++) {
        int t = i * NTH + tid;
        float4 tr = trow[t];
        float cr = __shfl_down(cuer[i], 1);
        if (lane == 63)
            cr = (wid < NW - 1) ? s_cedge[wid + 1][i]
                                : ((i + 1 < EPT) ? s_cedge[0][i + 1] : 1.f);
        float vv = 0.f, pp = 0.f;
        if (t < L) {
            float z1 = (tr.y - mean1) * istd1;
            float z3 = (tr.w - mean3) * istd3;
            vv = expf(log1pf(fmaxf(durr[i], 0.f)) + 0.45f * z1 + 0.3f * z3 + 0.2f * cr);
            float z0 = (tr.x - mean0) * istd0;
            float spv = fminf(fmaxf((cuer[i] - meanc) * istdc, -1.5f), 1.5f);
            pp = expf(1.1f * z0 + 1.5f * rb[i] + pcoef * spv);
        }
        v[i] = vv; ps[i] = pp;
        if (lane == 0)  s_vL[wid][i] = vv;
        if (lane == 63) s_vR[wid][i] = vv;
    }
    // clear radix hist buffer 0 under the same barrier
    for (int j = tid; j < NW * 256; j += NTH) s_hist[j] = 0u;
    __syncthreads();

    // ---- Phase 3b: smooth3 via shuffles + wave-edge LDS; sum (cuer, rb die here)
    float sm[EPT];
    float acc1[1] = {0.f};
#pragma unroll
    for (int i = 0; i < EPT; i++) {
        int t = i * NTH + tid;
        float vl = __shfl_up(v[i], 1);
        if (lane == 0)
            vl = (wid > 0) ? s_vR[wid - 1][i] : ((i > 0) ? s_vR[NW - 1][i - 1] : 0.f);
        float vr = __shfl_down(v[i], 1);
        if (lane == 63)
            vr = (wid < NW - 1) ? s_vL[wid + 1][i] : ((i + 1 < EPT) ? s_vL[0][i + 1] : 0.f);
        float smv = 0.f;
        if (t < L) smv = (vl + v[i] + vr) * (1.f / 3.f);
        sm[i] = smv; acc1[0] += smv;
    }
    block_reduce<1>(acc1, s_red, s_bc);
    const float spe_scale = speech_budget / fmaxf(s_bc[0], 1e-6f);

    // ---- Phase 4: exact radix select, ping-pong histograms (2 barriers/round)
    unsigned pref = 0u, cmaskk = 0u;
    unsigned kk = (unsigned)kint;
    unsigned cnt_eq = 0u;
    int cur = 0;
#pragma unroll 1
    for (int r = 0; r < 4; r++) {
        const int shift = 24 - 8 * r;
#pragma unroll
        for (int i = 0; i < EPT; i++) {
            unsigned b = __float_as_uint(ps[i]);
            if ((b & cmaskk) == pref)
                atomicAdd(&s_hist[cur * (NW * 256) + wid * 256 + ((b >> shift) & 0xFFu)], 1u);
        }
        __syncthreads();
        if (wid == 0) {
            unsigned base = lane * 4;
            unsigned h0 = 0, h1 = 0, h2 = 0, h3 = 0;
#pragma unroll
            for (int w = 0; w < NW; w++) {
                const unsigned* hb = &s_hist[cur * (NW * 256) + w * 256 + base];
                h0 += hb[0]; h1 += hb[1]; h2 += hb[2]; h3 += hb[3];
            }
            unsigned s = h0 + h1 + h2 + h3;
            unsigned vs = s;
#pragma unroll
            for (int off = 1; off < 64; off <<= 1) {
                unsigned u = __shfl_down(vs, off);
                if (lane + off < 64) vs += u;
            }
            unsigned vnext = __shfl_down(vs, 1);
            if (lane == 63) vnext = 0u;
            unsigned higher = vs - s;
            unsigned S3 = higher + h3;
            unsigned S2 = S3 + h2;
            unsigned S1 = S2 + h1;
            unsigned S0 = S1 + h0;
            if (S3 >= kk && vnext < kk)    { s_sel[0] = base + 3; s_sel[1] = vnext; s_sel[2] = S3; }
            else if (S2 >= kk && S3 < kk)  { s_sel[0] = base + 2; s_sel[1] = S3;    s_sel[2] = S2; }
            else if (S1 >= kk && S2 < kk)  { s_sel[0] = base + 1; s_sel[1] = S2;    s_sel[2] = S1; }
            else if (S0 >= kk && S1 < kk)  { s_sel[0] = base + 0; s_sel[1] = S1;    s_sel[2] = S0; }
        } else if (r < 3) {
            // other waves clear the next buffer while wave 0 scans
            for (int j = tid - 64; j < NW * 256; j += NTH - 64)
                s_hist[(cur ^ 1) * (NW * 256) + j] = 0u;
        }
        __syncthreads();
        pref |= s_sel[0] << shift;
        cmaskk |= 0xFFu << shift;
        kk -= s_sel[1];
        if (r == 3) cnt_eq = s_sel[2] - s_sel[1];
        cur ^= 1;
    }
    const unsigned thr_bits = pref;
    const unsigned keep_eq = kk;

    // ---- Phase 5: keep top-k (stable tie-break only if needed), sum kept
    float accp[1] = {0.f};
    if (cnt_eq == keep_eq) {
#pragma unroll
        for (int c = 0; c < EPT; c++) {
            unsigned b = __float_as_uint(ps[c]);
            float pv = (b >= thr_bits) ? ps[c] : 0.f;
            ps[c] = pv; accp[0] += pv;
        }
    } else {
        unsigned carry_eq = 0u;
#pragma unroll
        for (int c = 0; c < EPT; c++) {
            unsigned b = __float_as_uint(ps[c]);
            bool eq = (b == thr_bits);
            unsigned long long bal = __ballot(eq);
            unsigned lpre = (unsigned)__popcll(bal & ((1ull << lane) - 1ull));
            unsigned wc = (unsigned)__popcll(bal);
            if (lane == 0) s_wu[wid] = wc;
            __syncthreads();
            unsigned woff = 0u, tot = 0u;
#pragma unroll
            for (int w = 0; w < NW; w++) { unsigned x = s_wu[w]; if (w < wid) woff += x; tot += x; }
            __syncthreads();
            unsigned rank = carry_eq + woff + lpre;
            bool keep = (b > thr_bits) || (eq && rank < keep_eq);
            float pv = keep ? ps[c] : 0.f;
            ps[c] = pv; accp[0] += pv;
            carry_eq += tot;
        }
    }
    block_reduce<1>(accp, s_red, s_bc);
    const float pa_scale = pause_budget / fmaxf(s_bc[0], 1e-6f);

    // ---- Phase 6: writes + 2-barrier block scan
    const float inv_alloc = 1.f / fmaxf(speech_budget + pause_budget, 1e-6f);
#pragma unroll
    for (int c = 0; c < EPT; c++) {
        int t = c * NTH + tid;
        bool in = t < L;
        float spe = sm[c] * spe_scale;
        float pae = ps[c] * pa_scale;
        o_spe[t] = spe;
        o_pae[t] = pae;
        o_al[t] = (spe + pae) * inv_alloc;
        float x = in ? (spe + pae - durr[c]) : 0.f;
#pragma unroll
        for (int off = 1; off < 64; off <<= 1) {
            float u = __shfl_up(x, off);
            if (lane >= off) x += u;
        }
        sm[c] = x;                       // per-lane inclusive scan within wave
        if (lane == 63) s_part[c * NW + wid] = x;
    }
    __syncthreads();
    if (wid == 0) {   // scan 128 wave-partials: 2 per lane
        float a = s_part[2 * lane], b = s_part[2 * lane + 1];
        float pair = a + b;
        float inc = pair;
#pragma unroll
        for (int off = 1; off < 64; off <<= 1) {
            float u = __shfl_up(inc, off);
            if (lane >= off) inc += u;
        }
        float excl = inc - pair;
        s_offs[2 * lane] = excl;
        s_offs[2 * lane + 1] = excl + a;
    }
    __syncthreads();
#pragma unroll
    for (int c = 0; c < EPT; c++) {
        int t = c * NTH + tid;
        bool in = t < L;
        float incl = s_offs[c * NW + wid] + sm[c];
        o_pc[t] = in ? incl : 0.f;
        o_bk[t] = in ? fmaxf(incl, 0.f) : 0.f;
    }

    if (tid == 0) {
        o_sb[row] = speech_budget;
        o_pb[row] = pause_budget;
        o_cf[row] = conf;
    }
}

extern "C" void kernel_launch(void* const* d_in, const int* in_sizes, int n_in,
                              void* d_out, int out_size, void* d_ws, size_t ws_size,
                              hipStream_t stream) {
    const float* dur   = (const float*)d_in[0];
    const float* stats = (const float*)d_in[1];
    const float* trace = (const float*)d_in[2];
    const float* mask  = (const float*)d_in[3];
    const float* cue   = (const float*)d_in[4];
    float* out = (float*)d_out;

    teacher_kernel<<<dim3(BATCH), dim3(NTH), 0, stream>>>(dur, stats, trace, mask, cue, out);
}

// Round 5
// 83.574 us; speedup vs baseline: 2.4072x; 1.1312x over previous
//
#include <hip/hip_runtime.h>

#define T 8192
#define BATCH 512
#define NTH 1024
#define EPT 8
#define NW 16

template <int N>
__device__ __forceinline__ void block_reduce(float (&v)[N], float* s_red, float* s_bc) {
    int lane = threadIdx.x & 63, wid = threadIdx.x >> 6;
#pragma unroll
    for (int j = 0; j < N; j++) {
        float x = v[j];
#pragma unroll
        for (int off = 32; off; off >>= 1) x += __shfl_xor(x, off);
        if (lane == 0) s_red[wid * N + j] = x;
    }
    __syncthreads();
    if (threadIdx.x < N) {
        float s = 0.f;
#pragma unroll
        for (int w = 0; w < NW; w++) s += s_red[w * N + threadIdx.x];
        s_bc[threadIdx.x] = s;
    }
    __syncthreads();
}

__global__ __launch_bounds__(NTH) void teacher_kernel(
    const float* __restrict__ dur, const float* __restrict__ stats,
    const float* __restrict__ trace, const float* __restrict__ mask,
    const float* __restrict__ cue, float* __restrict__ out)
{
    const int row = blockIdx.x;
    const int tid = threadIdx.x;
    const int lane = tid & 63, wid = tid >> 6;

    __shared__ unsigned s_hist[2 * NW * 256];   // 32 KB ping-pong
    __shared__ float s_red[NW * 13];
    __shared__ float s_bc[16];
    __shared__ float s_vL[NW][EPT], s_vR[NW][EPT];
    __shared__ float s_part[EPT * NW];
    __shared__ float s_offs[EPT * NW];
    __shared__ unsigned s_sel[4];
    __shared__ unsigned s_wu[NW];

    const size_t BT = (size_t)BATCH * T;
    const size_t rbase = (size_t)row * T;
    const float* drow = dur + rbase;
    const float* mrow = mask + rbase;
    const float* crow = cue + rbase;
    const float4* trow = (const float4*)(trace + rbase * 4);

    float* o_spe = out + rbase;
    float* o_pae = out + BT + rbase;
    float* o_sb  = out + 2 * BT;
    float* o_pb  = out + 2 * BT + BATCH;
    float* o_al  = out + 2 * BT + 2 * BATCH + rbase;
    float* o_cf  = out + 3 * BT + 2 * BATCH;
    float4* o_tc = ((float4*)(out + 3 * BT + 3 * BATCH)) + rbase;
    float* o_pc  = out + 7 * BT + 3 * BATCH + rbase;
    float* o_bk  = out + 8 * BT + 3 * BATCH + rbase;

    float durr[EPT];

    // ---- Phase 1: single full input read, write trace_ctx, 12 masked sums + stats max
    // acc: 0:m 1:d*m 2:tx*m 3:tx2*m 4:ty*m 5:ty2*m 6:tz*m 7:tz2*m 8:tw*m 9:tw2*m 10:c*m 11:c*tz*m
    float statmax = (tid < BATCH) ? fminf(fmaxf(stats[tid * 5 + 4], 0.f), 1.f) : 0.f;
    float acc[12];
#pragma unroll
    for (int j = 0; j < 12; j++) acc[j] = 0.f;
#pragma unroll
    for (int i = 0; i < EPT; i++) {
        int t = i * NTH + tid;
        float m = mrow[t];
        float d = drow[t];
        float c = crow[t];
        float4 tr = trow[t];
        durr[i] = d;
        o_tc[t] = make_float4(tr.x * m, tr.y * m, tr.z * m, tr.w * m);
        acc[0] += m;            acc[1] += d * m;
        acc[2] += tr.x * m;     acc[3] += tr.x * tr.x * m;
        acc[4] += tr.y * m;     acc[5] += tr.y * tr.y * m;
        acc[6] += tr.z * m;     acc[7] += tr.z * tr.z * m;
        acc[8] += tr.w * m;     acc[9] += tr.w * tr.w * m;
        acc[10] += c * m;       acc[11] += c * tr.z * m;
    }
    {
#pragma unroll
        for (int j = 0; j < 12; j++) {
            float x = acc[j];
#pragma unroll
            for (int off = 32; off; off >>= 1) x += __shfl_xor(x, off);
            if (lane == 0) s_red[wid * 13 + j] = x;
        }
        float mx = statmax;
#pragma unroll
        for (int off = 32; off; off >>= 1) mx = fmaxf(mx, __shfl_xor(mx, off));
        if (lane == 0) s_red[wid * 13 + 12] = mx;
        __syncthreads();
        if (tid < 13) {
            float s = s_red[tid];
#pragma unroll
            for (int w = 1; w < NW; w++) {
                float x = s_red[w * 13 + tid];
                s = (tid == 12) ? fmaxf(s, x) : (s + x);
            }
            s_bc[tid] = s;
        }
        __syncthreads();
    }
    const float visible = fmaxf(s_bc[0], 1.f);
    const float sum_d = s_bc[1];
    const float inv_vis = 1.f / visible;
    const float mean0 = s_bc[2] * inv_vis, ex20 = s_bc[3] * inv_vis;
    const float mean1 = s_bc[4] * inv_vis, ex21 = s_bc[5] * inv_vis;
    const float Sz    = s_bc[6];
    const float mean2 = Sz * inv_vis,      ex22 = s_bc[7] * inv_vis;
    const float mean3 = s_bc[8] * inv_vis, ex23 = s_bc[9] * inv_vis;
    const float n1    = s_bc[10];
    const float Scz   = s_bc[11];
    const float gmax  = s_bc[12];
    const float meanc = n1 * inv_vis;

    const float var1_raw = ex21 - mean1 * mean1;
    const float var2_raw = ex22 - mean2 * mean2;
    const float istd0 = 1.f / sqrtf(fmaxf(ex20 - mean0 * mean0, 1e-6f));
    const float istd1 = 1.f / sqrtf(fmaxf(var1_raw, 1e-6f));
    const float istd2 = 1.f / sqrtf(fmaxf(var2_raw, 1e-6f));
    const float istd3 = 1.f / sqrtf(fmaxf(ex23 - mean3 * mean3, 1e-6f));
    const float istdc = 1.f / sqrtf(fmaxf(meanc - meanc * meanc, 1e-6f));

    const int L = (int)(visible + 0.5f);

    const float st0 = stats[row * 5 + 0], st1 = stats[row * 5 + 1];
    const float st2 = stats[row * 5 + 2], st4 = stats[row * 5 + 4];

    const float src_total = fmaxf(sum_d, 1.f);
    const float src_mean = src_total * inv_vis;
    const float ref_ms = fmaxf(st2, 1.f);
    const float rate_scale = fminf(fmaxf(ref_ms / fmaxf(src_mean, 1.f), 0.55f), 1.95f);
    const float speech_budget = src_total * rate_scale;
    const float pause_ratio = fminf(fmaxf(st0, 0.f), 0.49f);
    const float boundary_ratio = fminf(fmaxf(st4, 0.f), 1.f);
    const float mean_pause = fmaxf(st1, 0.f);
    const float pfr = speech_budget * pause_ratio / fmaxf(1.f - pause_ratio, 0.2f);
    const float pfe = visible * boundary_ratio * mean_pause;
    float pause_budget = fmaxf(0.35f * pfr + 0.65f * pfe, 0.f);
    pause_budget = fminf(pause_budget, speech_budget * 0.8f);

    float conf = 0.2f + 0.3f * fminf(fmaxf(st0, 0.f), 1.f)
               + 0.25f * fminf(fmaxf(st4, 0.f), 1.f)
               + 0.2f * mean2
               + 0.1f * expf(-fmaxf(var1_raw, 0.f)) + 0.05f;
    conf = fminf(fmaxf(conf, 0.05f), 1.f);

    const float ratio = fminf(fmaxf(fmaxf(0.3f, gmax), 0.f), 1.f);
    int kint = (int)rintf(visible * ratio);
    kint = max(1, min(kint, L));

    // ---- Closed-form cosine gate (cue is 0/1: sp takes two values hi/lo)
    const float hi = fminf(fmaxf((1.f - meanc) * istdc, -1.5f), 1.5f);
    const float lo = fminf(fmaxf((0.f - meanc) * istdc, -1.5f), 1.5f);
    float pcoef;
    {
        float n0 = visible - n1;
        float sum_sp2 = hi * hi * n1 + lo * lo * n0;
        float sum_rb2 = istd2 * istd2 * visible * fmaxf(var2_raw, 0.f);
        float c1 = Scz - mean2 * n1;
        float c0 = (Sz - mean2 * visible) - c1;
        float dotv = istd2 * (hi * c1 + lo * c0);
        float xn = sqrtf(fmaxf(sum_sp2, 1e-6f));
        float yn = sqrtf(fmaxf(sum_rb2, 1e-6f));
        float agree = fminf(fmaxf(dotv / fmaxf(xn * yn, 1e-6f), -1.f), 1.f);
        float gate = 1.f / (1.f + expf(-(agree - 0.15f) * 4.f));
        pcoef = 0.35f * (0.05f + 0.5f * gate);
    }

    // ---- Phase 3: speech + pause scores (cue/trace reloads are L3-hot)
    float v[EPT], ps[EPT];
#pragma unroll
    for (int i = 0; i < EPT; i++) {
        int t = i * NTH + tid;
        float c = crow[t];
        float pf = (t == T - 1) ? 1.f : crow[t + 1];
        float4 tr = trow[t];
        float vv = 0.f, pp = 0.f;
        if (t < L) {
            float z1 = (tr.y - mean1) * istd1;
            float z3 = (tr.w - mean3) * istd3;
            vv = expf(log1pf(fmaxf(durr[i], 0.f)) + 0.45f * z1 + 0.3f * z3 + 0.2f * pf);
            float z0 = (tr.x - mean0) * istd0;
            float rbv = (tr.z - mean2) * istd2;
            float spv = lo + c * (hi - lo);
            pp = expf(1.1f * z0 + 1.5f * rbv + pcoef * spv);
        }
        v[i] = vv; ps[i] = pp;
        if (lane == 0)  s_vL[wid][i] = vv;
        if (lane == 63) s_vR[wid][i] = vv;
    }
    // clear radix hist buffer 0 under the same barrier
    for (int j = tid; j < NW * 256; j += NTH) s_hist[j] = 0u;
    __syncthreads();

    // ---- Phase 3b: smooth3 in place via shuffles + wave-edge LDS; sum
    float acc1[1] = {0.f};
#pragma unroll
    for (int i = 0; i < EPT; i++) {
        int t = i * NTH + tid;
        float vl = __shfl_up(v[i], 1);
        if (lane == 0)
            vl = (wid > 0) ? s_vR[wid - 1][i] : ((i > 0) ? s_vR[NW - 1][i - 1] : 0.f);
        float vr = __shfl_down(v[i], 1);
        if (lane == 63)
            vr = (wid < NW - 1) ? s_vL[wid + 1][i] : ((i + 1 < EPT) ? s_vL[0][i + 1] : 0.f);
        float smv = 0.f;
        if (t < L) smv = (vl + v[i] + vr) * (1.f / 3.f);
        v[i] = smv;                     // in place: v becomes smoothed score
        acc1[0] += smv;
    }
    block_reduce<1>(acc1, s_red, s_bc);
    const float spe_scale = speech_budget / fmaxf(s_bc[0], 1e-6f);

    // ---- Phase 4: exact radix select, ping-pong histograms (2 barriers/round)
    unsigned pref = 0u, cmaskk = 0u;
    unsigned kk = (unsigned)kint;
    unsigned cnt_eq = 0u;
    int cur = 0;
#pragma unroll 1
    for (int r = 0; r < 4; r++) {
        const int shift = 24 - 8 * r;
#pragma unroll
        for (int i = 0; i < EPT; i++) {
            unsigned b = __float_as_uint(ps[i]);
            if ((b & cmaskk) == pref)
                atomicAdd(&s_hist[cur * (NW * 256) + wid * 256 + ((b >> shift) & 0xFFu)], 1u);
        }
        __syncthreads();
        if (wid == 0) {
            unsigned base = lane * 4;
            unsigned h0 = 0, h1 = 0, h2 = 0, h3 = 0;
#pragma unroll
            for (int w = 0; w < NW; w++) {
                const unsigned* hb = &s_hist[cur * (NW * 256) + w * 256 + base];
                h0 += hb[0]; h1 += hb[1]; h2 += hb[2]; h3 += hb[3];
            }
            unsigned s = h0 + h1 + h2 + h3;
            unsigned vs = s;
#pragma unroll
            for (int off = 1; off < 64; off <<= 1) {
                unsigned u = __shfl_down(vs, off);
                if (lane + off < 64) vs += u;
            }
            unsigned vnext = __shfl_down(vs, 1);
            if (lane == 63) vnext = 0u;
            unsigned higher = vs - s;
            unsigned S3 = higher + h3;
            unsigned S2 = S3 + h2;
            unsigned S1 = S2 + h1;
            unsigned S0 = S1 + h0;
            if (S3 >= kk && vnext < kk)    { s_sel[0] = base + 3; s_sel[1] = vnext; s_sel[2] = S3; }
            else if (S2 >= kk && S3 < kk)  { s_sel[0] = base + 2; s_sel[1] = S3;    s_sel[2] = S2; }
            else if (S1 >= kk && S2 < kk)  { s_sel[0] = base + 1; s_sel[1] = S2;    s_sel[2] = S1; }
            else if (S0 >= kk && S1 < kk)  { s_sel[0] = base + 0; s_sel[1] = S1;    s_sel[2] = S0; }
        } else if (r < 3) {
            for (int j = tid - 64; j < NW * 256; j += NTH - 64)
                s_hist[(cur ^ 1) * (NW * 256) + j] = 0u;
        }
        __syncthreads();
        pref |= s_sel[0] << shift;
        cmaskk |= 0xFFu << shift;
        kk -= s_sel[1];
        if (r == 3) cnt_eq = s_sel[2] - s_sel[1];
        cur ^= 1;
    }
    const unsigned thr_bits = pref;
    const unsigned keep_eq = kk;

    // ---- Phase 5: keep top-k (stable tie-break only if needed), sum kept
    float accp[1] = {0.f};
    if (cnt_eq == keep_eq) {
#pragma unroll
        for (int c = 0; c < EPT; c++) {
            unsigned b = __float_as_uint(ps[c]);
            float pv = (b >= thr_bits) ? ps[c] : 0.f;
            ps[c] = pv; accp[0] += pv;
        }
    } else {
        unsigned carry_eq = 0u;
#pragma unroll
        for (int c = 0; c < EPT; c++) {
            unsigned b = __float_as_uint(ps[c]);
            bool eq = (b == thr_bits);
            unsigned long long bal = __ballot(eq);
            unsigned lpre = (unsigned)__popcll(bal & ((1ull << lane) - 1ull));
            unsigned wc = (unsigned)__popcll(bal);
            if (lane == 0) s_wu[wid] = wc;
            __syncthreads();
            unsigned woff = 0u, tot = 0u;
#pragma unroll
            for (int w = 0; w < NW; w++) { unsigned x = s_wu[w]; if (w < wid) woff += x; tot += x; }
            __syncthreads();
            unsigned rank = carry_eq + woff + lpre;
            bool keep = (b > thr_bits) || (eq && rank < keep_eq);
            float pv = keep ? ps[c] : 0.f;
            ps[c] = pv; accp[0] += pv;
            carry_eq += tot;
        }
    }
    block_reduce<1>(accp, s_red, s_bc);
    const float pa_scale = pause_budget / fmaxf(s_bc[0], 1e-6f);

    // ---- Phase 6: writes + 2-barrier block scan
    const float inv_alloc = 1.f / fmaxf(speech_budget + pause_budget, 1e-6f);
#pragma unroll
    for (int c = 0; c < EPT; c++) {
        int t = c * NTH + tid;
        bool in = t < L;
        float spe = v[c] * spe_scale;
        float pae = ps[c] * pa_scale;
        o_spe[t] = spe;
        o_pae[t] = pae;
        o_al[t] = (spe + pae) * inv_alloc;
        float x = in ? (spe + pae - durr[c]) : 0.f;
#pragma unroll
        for (int off = 1; off < 64; off <<= 1) {
            float u = __shfl_up(x, off);
            if (lane >= off) x += u;
        }
        v[c] = x;                        // per-lane inclusive scan within wave
        if (lane == 63) s_part[c * NW + wid] = x;
    }
    __syncthreads();
    if (wid == 0) {   // scan 128 wave-partials: 2 per lane
        float a = s_part[2 * lane], b = s_part[2 * lane + 1];
        float pair = a + b;
        float inc = pair;
#pragma unroll
        for (int off = 1; off < 64; off <<= 1) {
            float u = __shfl_up(inc, off);
            if (lane >= off) inc += u;
        }
        float excl = inc - pair;
        s_offs[2 * lane] = excl;
        s_offs[2 * lane + 1] = excl + a;
    }
    __syncthreads();
#pragma unroll
    for (int c = 0; c < EPT; c++) {
        int t = c * NTH + tid;
        bool in = t < L;
        float incl = s_offs[c * NW + wid] + v[c];
        o_pc[t] = in ? incl : 0.f;
        o_bk[t] = in ? fmaxf(incl, 0.f) : 0.f;
    }

    if (tid == 0) {
        o_sb[row] = speech_budget;
        o_pb[row] = pause_budget;
        o_cf[row] = conf;
    }
}

extern "C" void kernel_launch(void* const* d_in, const int* in_sizes, int n_in,
                              void* d_out, int out_size, void* d_ws, size_t ws_size,
                              hipStream_t stream) {
    const float* dur   = (const float*)d_in[0];
    const float* stats = (const float*)d_in[1];
    const float* trace = (const float*)d_in[2];
    const float* mask  = (const float*)d_in[3];
    const float* cue   = (const float*)d_in[4];
    float* out = (float*)d_out;

    teacher_kernel<<<dim3(BATCH), dim3(NTH), 0, stream>>>(dur, stats, trace, mask, cue, out);
}